// Round 1
// baseline (2157.384 us; speedup 1.0000x reference)
//
#include <hip/hip_runtime.h>
#include <hip/hip_bf16.h>

#define N_NODES 50000
#define N_EDGES 800000
#define HID 64
#define N_LAYERS 3
#define BN_EPS 1e-5f
#define SELF_W 2.0f

// ---------------- kernels ----------------

// deg[i] = 2.0 (improved self-loop weight)
__global__ void k_init_deg(float* __restrict__ deg) {
    int i = blockIdx.x * blockDim.x + threadIdx.x;
    if (i < N_NODES) deg[i] = SELF_W;
}

// deg[dst[e]] += w[e]
__global__ void k_deg_scatter(const int* __restrict__ dst, const float* __restrict__ w,
                              float* __restrict__ deg) {
    int e = blockIdx.x * blockDim.x + threadIdx.x;
    if (e < N_EDGES) atomicAdd(&deg[dst[e]], w[e]);
}

// dinv = rsqrt(deg) (deg >= 2 always); selfnorm = 2 * dinv^2
__global__ void k_dinv(float* __restrict__ deg, float* __restrict__ selfnorm) {
    int i = blockIdx.x * blockDim.x + threadIdx.x;
    if (i < N_NODES) {
        float d = deg[i];
        float di = (d > 0.f) ? rsqrtf(d) : 0.f;
        deg[i] = di;                 // deg buffer becomes dinv in place
        selfnorm[i] = SELF_W * di * di;
    }
}

// norm[e] = dinv[src]*w*dinv[dst]
__global__ void k_edge_norm(const int* __restrict__ src, const int* __restrict__ dst,
                            const float* __restrict__ w, const float* __restrict__ dinv,
                            float* __restrict__ norm) {
    int e = blockIdx.x * blockDim.x + threadIdx.x;
    if (e < N_EDGES) norm[e] = dinv[src[e]] * w[e] * dinv[dst[e]];
}

// lin = h @ W ; agg = lin * selfnorm (self-loop init) ; block 0 zeroes stats
__global__ void k_linear(const float* __restrict__ h, const float* __restrict__ W,
                         const float* __restrict__ selfnorm,
                         float* __restrict__ lin, float* __restrict__ agg,
                         float* __restrict__ stats) {
    __shared__ float sW[HID * HID];
    __shared__ float sh[4][HID];
    int tid = threadIdx.x;               // 256 threads = 4 rows x 64 cols
    for (int k = tid; k < HID * HID; k += 256) sW[k] = W[k];
    int r = tid >> 6, c = tid & 63;
    int row = blockIdx.x * 4 + r;
    if (row < N_NODES) sh[r][c] = h[row * HID + c];
    if (blockIdx.x == 0 && tid < 128) stats[tid] = 0.f;
    __syncthreads();
    if (row < N_NODES) {
        float acc = 0.f;
#pragma unroll
        for (int k = 0; k < HID; ++k) acc = fmaf(sh[r][k], sW[k * HID + c], acc);
        lin[row * HID + c] = acc;
        agg[row * HID + c] = acc * selfnorm[row];
    }
}

// agg[dst,:] += lin[src,:] * norm[e]   (4 features per thread, float4 gather)
__global__ void k_scatter(const int* __restrict__ src, const int* __restrict__ dst,
                          const float* __restrict__ norm, const float* __restrict__ lin,
                          float* __restrict__ agg) {
    long long idx = (long long)blockIdx.x * blockDim.x + threadIdx.x;
    int e = (int)(idx >> 4);
    int c4 = ((int)idx & 15) << 2;
    if (e < N_EDGES) {
        float n = norm[e];
        int s = src[e], d = dst[e];
        float4 v = *reinterpret_cast<const float4*>(lin + (size_t)s * HID + c4);
        float* ap = agg + (size_t)d * HID + c4;
        atomicAdd(ap + 0, v.x * n);
        atomicAdd(ap + 1, v.y * n);
        atomicAdd(ap + 2, v.z * n);
        atomicAdd(ap + 3, v.w * n);
    }
}

// per-column sum and sumsq of t = relu(agg + b)
__global__ void k_bn_stats(const float* __restrict__ agg, const float* __restrict__ b,
                           float* __restrict__ stats) {
    int c = threadIdx.x & 63, rr = threadIdx.x >> 6;    // 256 thr = 4 rows x 64 cols
    float bc = b[c];
    float s = 0.f, s2 = 0.f;
    for (int row = blockIdx.x * 4 + rr; row < N_NODES; row += gridDim.x * 4) {
        float t = agg[(size_t)row * HID + c] + bc;
        t = t > 0.f ? t : 0.f;
        s += t; s2 += t * t;
    }
    __shared__ float ls[4][HID], ls2[4][HID];
    ls[rr][c] = s; ls2[rr][c] = s2;
    __syncthreads();
    if (threadIdx.x < HID) {
        float ts  = ls[0][c] + ls[1][c] + ls[2][c] + ls[3][c];
        float ts2 = ls2[0][c] + ls2[1][c] + ls2[2][c] + ls2[3][c];
        atomicAdd(&stats[c], ts);
        atomicAdd(&stats[HID + c], ts2);
    }
}

// out = (relu(agg+b) - mu) * rsqrt(var+eps) * gamma + beta
__global__ void k_bn_apply(const float* __restrict__ agg, const float* __restrict__ b,
                           const float* __restrict__ gamma, const float* __restrict__ beta,
                           const float* __restrict__ stats, float* __restrict__ out) {
    int idx = blockIdx.x * blockDim.x + threadIdx.x;
    if (idx < N_NODES * HID) {
        int c = idx & 63;
        const float invn = 1.0f / (float)N_NODES;
        float mu = stats[c] * invn;
        float var = stats[HID + c] * invn - mu * mu;
        float ivar = rsqrtf(var + BN_EPS);
        float t = agg[idx] + b[c];
        t = t > 0.f ? t : 0.f;
        out[idx] = (t - mu) * ivar * gamma[c] + beta[c];
    }
}

// ---------------- launch ----------------

extern "C" void kernel_launch(void* const* d_in, const int* in_sizes, int n_in,
                              void* d_out, int out_size, void* d_ws, size_t ws_size,
                              hipStream_t stream) {
    const float* x      = (const float*)d_in[0];   // [N, 64]
    const int*   ei     = (const int*)d_in[1];     // [2, E] int32
    const float* w      = (const float*)d_in[2];   // [E]
    const float* Ws     = (const float*)d_in[3];   // [3, 64, 64]
    const float* bs     = (const float*)d_in[4];   // [3, 64]
    const float* gammas = (const float*)d_in[5];   // [3, 64]
    const float* betas  = (const float*)d_in[6];   // [3, 64]
    float* out = (float*)d_out;                    // [3, N, 64]

    const int* src = ei;
    const int* dst = ei + N_EDGES;

    // workspace layout (floats)
    float* ws = (float*)d_ws;
    float* dinv     = ws;                          // N   (deg -> dinv in place)
    float* selfnorm = dinv + N_NODES;              // N
    float* norm     = selfnorm + N_NODES;          // E
    float* lin      = norm + N_EDGES;              // N*64
    float* agg      = lin + (size_t)N_NODES * HID; // N*64
    float* stats    = agg + (size_t)N_NODES * HID; // 128

    const int T = 256;
    const int gN  = (N_NODES + T - 1) / T;
    const int gE  = (N_EDGES + T - 1) / T;
    const int gR  = N_NODES / 4;                       // 12500 (N divisible by 4)
    const int gS  = (int)(((long long)N_EDGES * 16 + T - 1) / T); // 50000
    const int gA  = (N_NODES * HID + T - 1) / T;       // 12500

    // ---- graph-invariant precompute (deg / dinv / edge norms) ----
    k_init_deg<<<gN, T, 0, stream>>>(dinv);
    k_deg_scatter<<<gE, T, 0, stream>>>(dst, w, dinv);
    k_dinv<<<gN, T, 0, stream>>>(dinv, selfnorm);
    k_edge_norm<<<gE, T, 0, stream>>>(src, dst, w, dinv, norm);

    // ---- layers ----
    for (int L = 0; L < N_LAYERS; ++L) {
        const float* h = (L == 0) ? x : (out + (size_t)(L - 1) * N_NODES * HID);
        float* outL = out + (size_t)L * N_NODES * HID;
        const float* W  = Ws + (size_t)L * HID * HID;
        const float* b  = bs + (size_t)L * HID;
        const float* g  = gammas + (size_t)L * HID;
        const float* bt = betas + (size_t)L * HID;

        k_linear<<<gR, T, 0, stream>>>(h, W, selfnorm, lin, agg, stats);
        k_scatter<<<gS, T, 0, stream>>>(src, dst, norm, lin, agg);
        k_bn_stats<<<256, T, 0, stream>>>(agg, b, stats);
        k_bn_apply<<<gA, T, 0, stream>>>(agg, b, g, bt, stats, outL);
    }
}

// Round 2
// 440.050 us; speedup vs baseline: 4.9026x; 4.9026x over previous
//
#include <hip/hip_runtime.h>
#include <hip/hip_bf16.h>

#define N_NODES 50000
#define N_EDGES 800000
#define HID 64
#define N_LAYERS 3
#define BN_EPS 1e-5f
#define SELF_W 2.0f
#define NB_SCAN 196   // ceil(50000/256)

// ---------------- precompute kernels (graph-invariant) ----------------

// deg=2.0 (self-loop weight), cnt=0, stats (3 layers x 128) = 0
__global__ void k_init(float* __restrict__ deg, int* __restrict__ cnt,
                       float* __restrict__ stats) {
    int i = blockIdx.x * blockDim.x + threadIdx.x;
    if (i < N_NODES) { deg[i] = SELF_W; cnt[i] = 0; }
    if (i < N_LAYERS * 2 * HID) stats[i] = 0.f;
}

// weighted degree + integer in-degree histogram
__global__ void k_hist(const int* __restrict__ dst, const float* __restrict__ w,
                       float* __restrict__ deg, int* __restrict__ cnt) {
    int e = blockIdx.x * blockDim.x + threadIdx.x;
    if (e < N_EDGES) {
        int d = dst[e];
        atomicAdd(&deg[d], w[e]);
        atomicAdd(&cnt[d], 1);
    }
}

// dinv = rsqrt(deg); selfnorm = 2*dinv^2
__global__ void k_dinv(float* __restrict__ deg, float* __restrict__ selfnorm) {
    int i = blockIdx.x * blockDim.x + threadIdx.x;
    if (i < N_NODES) {
        float d = deg[i];
        float di = (d > 0.f) ? rsqrtf(d) : 0.f;
        deg[i] = di;                  // becomes dinv in place
        selfnorm[i] = SELF_W * di * di;
    }
}

// block-local exclusive scan of cnt -> rowptr; block sums -> partials
__global__ void k_scan1(const int* __restrict__ cnt, int* __restrict__ rowptr,
                        int* __restrict__ partials) {
    __shared__ int sh[256];
    int tid = threadIdx.x;
    int i = blockIdx.x * 256 + tid;
    int v = (i < N_NODES) ? cnt[i] : 0;
    sh[tid] = v;
    __syncthreads();
    for (int off = 1; off < 256; off <<= 1) {
        int t = (tid >= off) ? sh[tid - off] : 0;
        __syncthreads();
        sh[tid] += t;
        __syncthreads();
    }
    if (i < N_NODES) rowptr[i] = sh[tid] - v;     // exclusive within block
    if (tid == 255) partials[blockIdx.x] = sh[255];
}

// exclusive scan of the NB_SCAN block partials (single block)
__global__ void k_scan2(int* __restrict__ partials) {
    __shared__ int sh[256];
    int tid = threadIdx.x;
    int v = (tid < NB_SCAN) ? partials[tid] : 0;
    sh[tid] = v;
    __syncthreads();
    for (int off = 1; off < 256; off <<= 1) {
        int t = (tid >= off) ? sh[tid - off] : 0;
        __syncthreads();
        sh[tid] += t;
        __syncthreads();
    }
    if (tid < NB_SCAN) partials[tid] = sh[tid] - v;  // exclusive
}

// add block offsets; cursor = rowptr
__global__ void k_scan3(int* __restrict__ rowptr, const int* __restrict__ partials,
                        int* __restrict__ cursor) {
    int i = blockIdx.x * 256 + threadIdx.x;
    if (i < N_NODES) {
        int r = rowptr[i] + partials[blockIdx.x];
        rowptr[i] = r;
        cursor[i] = r;
    }
}

// CSR fill: entries[pos] = (src, norm) bucketed by dst
__global__ void k_fill(const int* __restrict__ src, const int* __restrict__ dst,
                       const float* __restrict__ w, const float* __restrict__ dinv,
                       int* __restrict__ cursor, float2* __restrict__ entries) {
    int e = blockIdx.x * blockDim.x + threadIdx.x;
    if (e < N_EDGES) {
        int s = src[e], d = dst[e];
        float n = dinv[s] * w[e] * dinv[d];
        int pos = atomicAdd(&cursor[d], 1);
        entries[pos] = make_float2(__int_as_float(s), n);
    }
}

// ---------------- per-layer kernels ----------------

// lin = h @ W   (256 thr = 4 rows x 64 cols; W staged in LDS)
__global__ void k_linear(const float* __restrict__ h, const float* __restrict__ W,
                         float* __restrict__ lin) {
    __shared__ float sW[HID * HID];
    __shared__ float sh[4][HID];
    int tid = threadIdx.x;
    for (int k = tid; k < HID * HID; k += 256) sW[k] = W[k];
    int r = tid >> 6, c = tid & 63;
    int row = blockIdx.x * 4 + r;
    if (row < N_NODES) sh[r][c] = h[(size_t)row * HID + c];
    __syncthreads();
    if (row < N_NODES) {
        float acc = 0.f;
#pragma unroll
        for (int k = 0; k < HID; ++k) acc = fmaf(sh[r][k], sW[k * HID + c], acc);
        lin[(size_t)row * HID + c] = acc;
    }
}

// gather-aggregate: one wave per node, lane = feature.
// out = relu( selfnorm*lin[node] + sum_e norm_e * lin[src_e] + b )
__global__ void k_gather(const float* __restrict__ lin, const float2* __restrict__ entries,
                         const int* __restrict__ rowptr, const int* __restrict__ cnt,
                         const float* __restrict__ selfnorm, const float* __restrict__ b,
                         float* __restrict__ out) {
    int wid = (blockIdx.x * blockDim.x + threadIdx.x) >> 6;
    int lane = threadIdx.x & 63;
    if (wid >= N_NODES) return;
    int node = wid;
    float acc = lin[(size_t)node * HID + lane] * selfnorm[node];
    int start = rowptr[node];
    int c = cnt[node];
    const float2* ep = entries + start;
    int k = 0;
    for (; k + 1 < c; k += 2) {
        float2 e0 = ep[k];
        float2 e1 = ep[k + 1];
        float v0 = lin[(size_t)__float_as_int(e0.x) * HID + lane];
        float v1 = lin[(size_t)__float_as_int(e1.x) * HID + lane];
        acc = fmaf(v0, e0.y, acc);
        acc = fmaf(v1, e1.y, acc);
    }
    if (k < c) {
        float2 e0 = ep[k];
        float v0 = lin[(size_t)__float_as_int(e0.x) * HID + lane];
        acc = fmaf(v0, e0.y, acc);
    }
    float t = acc + b[lane];
    out[(size_t)node * HID + lane] = t > 0.f ? t : 0.f;
}

// per-column sum/sumsq of h (already relu'd)
__global__ void k_bn_stats(const float* __restrict__ h, float* __restrict__ stats) {
    int c = threadIdx.x & 63, rr = threadIdx.x >> 6;
    float s = 0.f, s2 = 0.f;
    for (int row = blockIdx.x * 4 + rr; row < N_NODES; row += gridDim.x * 4) {
        float t = h[(size_t)row * HID + c];
        s += t; s2 += t * t;
    }
    __shared__ float ls[4][HID], ls2[4][HID];
    ls[rr][c] = s; ls2[rr][c] = s2;
    __syncthreads();
    if (threadIdx.x < HID) {
        atomicAdd(&stats[c],       ls[0][c] + ls[1][c] + ls[2][c] + ls[3][c]);
        atomicAdd(&stats[HID + c], ls2[0][c] + ls2[1][c] + ls2[2][c] + ls2[3][c]);
    }
}

// in-place: h = (h - mu) * rsqrt(var+eps) * gamma + beta
__global__ void k_bn_apply(float* __restrict__ h, const float* __restrict__ gamma,
                           const float* __restrict__ beta, const float* __restrict__ stats) {
    int idx = blockIdx.x * blockDim.x + threadIdx.x;
    if (idx < N_NODES * HID) {
        int c = idx & 63;
        const float invn = 1.0f / (float)N_NODES;
        float mu = stats[c] * invn;
        float var = stats[HID + c] * invn - mu * mu;
        float ivar = rsqrtf(var + BN_EPS);
        h[idx] = (h[idx] - mu) * ivar * gamma[c] + beta[c];
    }
}

// ---------------- launch ----------------

extern "C" void kernel_launch(void* const* d_in, const int* in_sizes, int n_in,
                              void* d_out, int out_size, void* d_ws, size_t ws_size,
                              hipStream_t stream) {
    const float* x      = (const float*)d_in[0];   // [N, 64]
    const int*   ei     = (const int*)d_in[1];     // [2, E] int32
    const float* w      = (const float*)d_in[2];   // [E]
    const float* Ws     = (const float*)d_in[3];   // [3, 64, 64]
    const float* bs     = (const float*)d_in[4];   // [3, 64]
    const float* gammas = (const float*)d_in[5];   // [3, 64]
    const float* betas  = (const float*)d_in[6];   // [3, 64]
    float* out = (float*)d_out;                    // [3, N, 64] fp32

    const int* src = ei;
    const int* dst = ei + N_EDGES;

    // workspace layout (4-byte units; entries first for 8B alignment)
    float*  ws       = (float*)d_ws;
    float2* entries  = (float2*)ws;                         // E * 2 floats
    float*  lin      = ws + (size_t)2 * N_EDGES;            // N*64
    float*  dinv     = lin + (size_t)N_NODES * HID;         // N (deg -> dinv)
    float*  selfnorm = dinv + N_NODES;                      // N
    int*    cnt      = (int*)(selfnorm + N_NODES);          // N
    int*    rowptr   = cnt + N_NODES;                       // N
    int*    cursor   = rowptr + N_NODES;                    // N
    int*    partials = cursor + N_NODES;                    // 256
    float*  stats    = (float*)(partials + 256);            // 3 * 128

    const int T = 256;
    const int gN = (N_NODES + T - 1) / T;                   // 196
    const int gE = (N_EDGES + T - 1) / T;                   // 3125
    const int gR = (N_NODES + 3) / 4;                       // 12500
    const int gW = (N_NODES * 64 + T - 1) / T;              // 12500 (wave per node)
    const int gA = (N_NODES * HID + T - 1) / T;             // 12500

    // ---- graph-invariant precompute ----
    k_init<<<gN, T, 0, stream>>>(dinv, cnt, stats);
    k_hist<<<gE, T, 0, stream>>>(dst, w, dinv, cnt);
    k_dinv<<<gN, T, 0, stream>>>(dinv, selfnorm);
    k_scan1<<<NB_SCAN, T, 0, stream>>>(cnt, rowptr, partials);
    k_scan2<<<1, T, 0, stream>>>(partials);
    k_scan3<<<NB_SCAN, T, 0, stream>>>(rowptr, partials, cursor);
    k_fill<<<gE, T, 0, stream>>>(src, dst, w, dinv, cursor, entries);

    // ---- layers ----
    for (int L = 0; L < N_LAYERS; ++L) {
        const float* h = (L == 0) ? x : (out + (size_t)(L - 1) * N_NODES * HID);
        float* outL = out + (size_t)L * N_NODES * HID;
        const float* W  = Ws + (size_t)L * HID * HID;
        const float* b  = bs + (size_t)L * HID;
        const float* g  = gammas + (size_t)L * HID;
        const float* bt = betas + (size_t)L * HID;
        float* statsL = stats + (size_t)L * 2 * HID;

        k_linear<<<gR, T, 0, stream>>>(h, W, lin);
        k_gather<<<gW, T, 0, stream>>>(lin, entries, rowptr, cnt, selfnorm, b, outL);
        k_bn_stats<<<256, T, 0, stream>>>(outL, statsL);
        k_bn_apply<<<gA, T, 0, stream>>>(outL, g, bt, statsL);
    }
}

// Round 3
// 355.250 us; speedup vs baseline: 6.0729x; 1.2387x over previous
//
#include <hip/hip_runtime.h>
#include <hip/hip_bf16.h>

#define N_NODES 50000
#define N_EDGES 800000
#define HID 64
#define N_LAYERS 3
#define BN_EPS 1e-5f
#define SELF_W 2.0f
#define NB_SCAN 196   // ceil(50000/256)
#define FPSCALE 16777216.0f          // 2^24
#define FPINV   (1.0f / 16777216.0f)
#define MASK40  0xFFFFFFFFFFull

// ---------------- precompute kernels (graph-invariant) ----------------

// packed (cnt<<40 | fixed-point wsum) = 0; stats (3 layers x 128) = 0
__global__ void k_init(unsigned long long* __restrict__ packed, float* __restrict__ stats) {
    int i = blockIdx.x * blockDim.x + threadIdx.x;
    if (i < N_NODES) packed[i] = 0ull;
    if (i < N_LAYERS * 2 * HID) stats[i] = 0.f;
}

// single 64-bit atomic per edge: count in high 24 bits, 24.16? no: 40-bit fixed
__global__ void k_hist(const int* __restrict__ dst, const float* __restrict__ w,
                       unsigned long long* __restrict__ packed) {
    int e = blockIdx.x * blockDim.x + threadIdx.x;
    if (e < N_EDGES) {
        unsigned q = (unsigned)(w[e] * FPSCALE + 0.5f);
        atomicAdd(&packed[dst[e]], (1ull << 40) | (unsigned long long)q);
    }
}

// unpack: cnt, dinv = rsqrt(2 + wsum), selfnorm = 2*dinv^2
__global__ void k_unpack(const unsigned long long* __restrict__ packed,
                         float* __restrict__ dinv, float* __restrict__ selfnorm,
                         int* __restrict__ cnt) {
    int i = blockIdx.x * blockDim.x + threadIdx.x;
    if (i < N_NODES) {
        unsigned long long p = packed[i];
        float deg = SELF_W + (float)(p & MASK40) * FPINV;
        float di = rsqrtf(deg);          // deg >= 2 always
        dinv[i] = di;
        selfnorm[i] = SELF_W * di * di;
        cnt[i] = (int)(p >> 40);
    }
}

// block-local exclusive scan of cnt -> rowptr; block sums -> partials
__global__ void k_scan1(const int* __restrict__ cnt, int* __restrict__ rowptr,
                        int* __restrict__ partials) {
    __shared__ int sh[256];
    int tid = threadIdx.x;
    int i = blockIdx.x * 256 + tid;
    int v = (i < N_NODES) ? cnt[i] : 0;
    sh[tid] = v;
    __syncthreads();
    for (int off = 1; off < 256; off <<= 1) {
        int t = (tid >= off) ? sh[tid - off] : 0;
        __syncthreads();
        sh[tid] += t;
        __syncthreads();
    }
    if (i < N_NODES) rowptr[i] = sh[tid] - v;
    if (tid == 255) partials[blockIdx.x] = sh[255];
}

__global__ void k_scan2(int* __restrict__ partials) {
    __shared__ int sh[256];
    int tid = threadIdx.x;
    int v = (tid < NB_SCAN) ? partials[tid] : 0;
    sh[tid] = v;
    __syncthreads();
    for (int off = 1; off < 256; off <<= 1) {
        int t = (tid >= off) ? sh[tid - off] : 0;
        __syncthreads();
        sh[tid] += t;
        __syncthreads();
    }
    if (tid < NB_SCAN) partials[tid] = sh[tid] - v;
}

__global__ void k_scan3(int* __restrict__ rowptr, const int* __restrict__ partials,
                        int* __restrict__ cursor) {
    int i = blockIdx.x * 256 + threadIdx.x;
    if (i < N_NODES) {
        int r = rowptr[i] + partials[blockIdx.x];
        rowptr[i] = r;
        cursor[i] = r;
    }
}

// CSR fill: entries[pos] = (src, norm) bucketed by dst
__global__ void k_fill(const int* __restrict__ src, const int* __restrict__ dst,
                       const float* __restrict__ w, const float* __restrict__ dinv,
                       int* __restrict__ cursor, float2* __restrict__ entries) {
    int e = blockIdx.x * blockDim.x + threadIdx.x;
    if (e < N_EDGES) {
        int s = src[e], d = dst[e];
        float n = dinv[s] * w[e] * dinv[d];
        int pos = atomicAdd(&cursor[d], 1);
        entries[pos] = make_float2(__int_as_float(s), n);
    }
}

// ---------------- per-layer kernels ----------------

// lin = h @ W   (256 thr = 4 rows x 64 cols; W staged in LDS)
__global__ void k_linear(const float* __restrict__ h, const float* __restrict__ W,
                         float* __restrict__ lin) {
    __shared__ float sW[HID * HID];
    __shared__ float sh[4][HID];
    int tid = threadIdx.x;
    for (int k = tid; k < HID * HID; k += 256) sW[k] = W[k];
    int r = tid >> 6, c = tid & 63;
    int row = blockIdx.x * 4 + r;
    if (row < N_NODES) sh[r][c] = h[(size_t)row * HID + c];
    __syncthreads();
    if (row < N_NODES) {
        float acc = 0.f;
#pragma unroll
        for (int k = 0; k < HID; ++k) acc = fmaf(sh[r][k], sW[k * HID + c], acc);
        lin[(size_t)row * HID + c] = acc;
    }
}

// gather-aggregate: one wave per node, lane = feature; scalar-path entries.
// out = relu( selfnorm*lin[node] + sum_e norm_e * lin[src_e] + b )
__global__ void k_gather(const float* __restrict__ lin, const float2* __restrict__ entries,
                         const int* __restrict__ rowptr, const int* __restrict__ cnt,
                         const float* __restrict__ selfnorm, const float* __restrict__ b,
                         float* __restrict__ out) {
    // wave slot made explicitly wave-uniform so node/rowptr/cnt/entry loads scalarize
    int wslot = __builtin_amdgcn_readfirstlane((int)(threadIdx.x >> 6));
    int node = blockIdx.x * 4 + wslot;
    int lane = threadIdx.x & 63;
    if (node >= N_NODES) return;
    float acc = lin[(size_t)node * HID + lane] * selfnorm[node];
    int start = rowptr[node];
    int c = cnt[node];
    const float2* ep = entries + start;
    int k = 0;
    for (; k + 3 < c; k += 4) {
        float2 e0 = ep[k];
        float2 e1 = ep[k + 1];
        float2 e2 = ep[k + 2];
        float2 e3 = ep[k + 3];
        float v0 = lin[(size_t)__float_as_int(e0.x) * HID + lane];
        float v1 = lin[(size_t)__float_as_int(e1.x) * HID + lane];
        float v2 = lin[(size_t)__float_as_int(e2.x) * HID + lane];
        float v3 = lin[(size_t)__float_as_int(e3.x) * HID + lane];
        acc = fmaf(v0, e0.y, acc);
        acc = fmaf(v1, e1.y, acc);
        acc = fmaf(v2, e2.y, acc);
        acc = fmaf(v3, e3.y, acc);
    }
    for (; k < c; ++k) {
        float2 e0 = ep[k];
        float v0 = lin[(size_t)__float_as_int(e0.x) * HID + lane];
        acc = fmaf(v0, e0.y, acc);
    }
    float t = acc + b[lane];
    out[(size_t)node * HID + lane] = t > 0.f ? t : 0.f;
}

// per-column sum/sumsq of h (already relu'd)
__global__ void k_bn_stats(const float* __restrict__ h, float* __restrict__ stats) {
    int c = threadIdx.x & 63, rr = threadIdx.x >> 6;
    float s = 0.f, s2 = 0.f;
    for (int row = blockIdx.x * 4 + rr; row < N_NODES; row += gridDim.x * 4) {
        float t = h[(size_t)row * HID + c];
        s += t; s2 += t * t;
    }
    __shared__ float ls[4][HID], ls2[4][HID];
    ls[rr][c] = s; ls2[rr][c] = s2;
    __syncthreads();
    if (threadIdx.x < HID) {
        atomicAdd(&stats[c],       ls[0][c] + ls[1][c] + ls[2][c] + ls[3][c]);
        atomicAdd(&stats[HID + c], ls2[0][c] + ls2[1][c] + ls2[2][c] + ls2[3][c]);
    }
}

// in-place: h = (h - mu) * rsqrt(var+eps) * gamma + beta
__global__ void k_bn_apply(float* __restrict__ h, const float* __restrict__ gamma,
                           const float* __restrict__ beta, const float* __restrict__ stats) {
    int idx = blockIdx.x * blockDim.x + threadIdx.x;
    if (idx < N_NODES * HID) {
        int c = idx & 63;
        const float invn = 1.0f / (float)N_NODES;
        float mu = stats[c] * invn;
        float var = stats[HID + c] * invn - mu * mu;
        float ivar = rsqrtf(var + BN_EPS);
        h[idx] = (h[idx] - mu) * ivar * gamma[c] + beta[c];
    }
}

// ---------------- launch ----------------

extern "C" void kernel_launch(void* const* d_in, const int* in_sizes, int n_in,
                              void* d_out, int out_size, void* d_ws, size_t ws_size,
                              hipStream_t stream) {
    const float* x      = (const float*)d_in[0];   // [N, 64]
    const int*   ei     = (const int*)d_in[1];     // [2, E] int32
    const float* w      = (const float*)d_in[2];   // [E]
    const float* Ws     = (const float*)d_in[3];   // [3, 64, 64]
    const float* bs     = (const float*)d_in[4];   // [3, 64]
    const float* gammas = (const float*)d_in[5];   // [3, 64]
    const float* betas  = (const float*)d_in[6];   // [3, 64]
    float* out = (float*)d_out;                    // [3, N, 64] fp32

    const int* src = ei;
    const int* dst = ei + N_EDGES;

    // workspace layout (8B-aligned items first)
    float*  ws       = (float*)d_ws;
    float2* entries  = (float2*)ws;                           // E * 8B
    unsigned long long* packed = (unsigned long long*)(ws + (size_t)2 * N_EDGES); // N * 8B
    float*  lin      = (float*)(packed + N_NODES);            // N*64
    float*  dinv     = lin + (size_t)N_NODES * HID;           // N
    float*  selfnorm = dinv + N_NODES;                        // N
    int*    cnt      = (int*)(selfnorm + N_NODES);            // N
    int*    rowptr   = cnt + N_NODES;                         // N
    int*    cursor   = rowptr + N_NODES;                      // N
    int*    partials = cursor + N_NODES;                      // 256
    float*  stats    = (float*)(partials + 256);              // 3 * 128

    const int T = 256;
    const int gN = (N_NODES + T - 1) / T;                     // 196
    const int gE = (N_EDGES + T - 1) / T;                     // 3125
    const int gR = (N_NODES + 3) / 4;                         // 12500
    const int gG = (N_NODES + 3) / 4;                         // 12500 (4 waves/block, wave per node)
    const int gA = (N_NODES * HID + T - 1) / T;               // 12500

    // ---- graph-invariant precompute ----
    k_init<<<gN, T, 0, stream>>>(packed, stats);
    k_hist<<<gE, T, 0, stream>>>(dst, w, packed);
    k_unpack<<<gN, T, 0, stream>>>(packed, dinv, selfnorm, cnt);
    k_scan1<<<NB_SCAN, T, 0, stream>>>(cnt, rowptr, partials);
    k_scan2<<<1, T, 0, stream>>>(partials);
    k_scan3<<<NB_SCAN, T, 0, stream>>>(rowptr, partials, cursor);
    k_fill<<<gE, T, 0, stream>>>(src, dst, w, dinv, cursor, entries);

    // ---- layers ----
    for (int L = 0; L < N_LAYERS; ++L) {
        const float* h = (L == 0) ? x : (out + (size_t)(L - 1) * N_NODES * HID);
        float* outL = out + (size_t)L * N_NODES * HID;
        const float* W  = Ws + (size_t)L * HID * HID;
        const float* b  = bs + (size_t)L * HID;
        const float* g  = gammas + (size_t)L * HID;
        const float* bt = betas + (size_t)L * HID;
        float* statsL = stats + (size_t)L * 2 * HID;

        k_linear<<<gR, T, 0, stream>>>(h, W, lin);
        k_gather<<<gG, T, 0, stream>>>(lin, entries, rowptr, cnt, selfnorm, b, outL);
        k_bn_stats<<<256, T, 0, stream>>>(outL, statsL);
        k_bn_apply<<<gA, T, 0, stream>>>(outL, g, bt, statsL);
    }
}

// Round 4
// 312.264 us; speedup vs baseline: 6.9089x; 1.1377x over previous
//
#include <hip/hip_runtime.h>
#include <hip/hip_bf16.h>

#define N_NODES 50000
#define N_EDGES 800000
#define HID 64
#define N_LAYERS 3
#define BN_EPS 1e-5f
#define SELF_W 2.0f
#define NB_SCAN 196   // ceil(50000/256)
#define FPSCALE 16777216.0f          // 2^24
#define FPINV   (1.0f / 16777216.0f)
#define MASK40  0xFFFFFFFFFFull

// ---------------- precompute kernels (graph-invariant) ----------------

// packed (cnt<<40 | fixed-point wsum) = 0; stats (3 layers x 128) = 0
__global__ void k_init(unsigned long long* __restrict__ packed, float* __restrict__ stats) {
    int i = blockIdx.x * blockDim.x + threadIdx.x;
    if (i < N_NODES) packed[i] = 0ull;
    if (i < N_LAYERS * 2 * HID) stats[i] = 0.f;
}

// one 64-bit atomic per edge; returned old count = rank of edge within its dst
__global__ void k_hist(const int* __restrict__ dst, const float* __restrict__ w,
                       unsigned long long* __restrict__ packed,
                       unsigned char* __restrict__ rank) {
    int e = blockIdx.x * blockDim.x + threadIdx.x;
    if (e < N_EDGES) {
        unsigned q = (unsigned)(w[e] * FPSCALE + 0.5f);
        unsigned long long old = atomicAdd(&packed[dst[e]], (1ull << 40) | (unsigned long long)q);
        rank[e] = (unsigned char)(old >> 40);
    }
}

// unpack packed -> dinv/selfnorm, and block-local exclusive scan of cnt -> rowptr
__global__ void k_scan1(const unsigned long long* __restrict__ packed,
                        float* __restrict__ dinv, float* __restrict__ selfnorm,
                        int* __restrict__ rowptr, int* __restrict__ partials) {
    __shared__ int sh[256];
    int tid = threadIdx.x;
    int i = blockIdx.x * 256 + tid;
    int v = 0;
    if (i < N_NODES) {
        unsigned long long p = packed[i];
        v = (int)(p >> 40);
        float deg = SELF_W + (float)(p & MASK40) * FPINV;
        float di = rsqrtf(deg);          // deg >= 2 always
        dinv[i] = di;
        selfnorm[i] = SELF_W * di * di;
    }
    sh[tid] = v;
    __syncthreads();
    for (int off = 1; off < 256; off <<= 1) {
        int t = (tid >= off) ? sh[tid - off] : 0;
        __syncthreads();
        sh[tid] += t;
        __syncthreads();
    }
    if (i < N_NODES) rowptr[i] = sh[tid] - v;
    if (tid == 255) partials[blockIdx.x] = sh[255];
}

__global__ void k_scan2(int* __restrict__ partials) {
    __shared__ int sh[256];
    int tid = threadIdx.x;
    int v = (tid < NB_SCAN) ? partials[tid] : 0;
    sh[tid] = v;
    __syncthreads();
    for (int off = 1; off < 256; off <<= 1) {
        int t = (tid >= off) ? sh[tid - off] : 0;
        __syncthreads();
        sh[tid] += t;
        __syncthreads();
    }
    if (tid < NB_SCAN) partials[tid] = sh[tid] - v;
}

__global__ void k_scan3(int* __restrict__ rowptr, const int* __restrict__ partials) {
    int i = blockIdx.x * 256 + threadIdx.x;
    if (i < N_NODES) rowptr[i] += partials[blockIdx.x];
    if (blockIdx.x == 0 && threadIdx.x == 0) rowptr[N_NODES] = N_EDGES;
}

// CSR fill, atomic-free: pos = rowptr[dst] + rank[e]
__global__ void k_fill(const int* __restrict__ src, const int* __restrict__ dst,
                       const float* __restrict__ w, const float* __restrict__ dinv,
                       const unsigned char* __restrict__ rank,
                       const int* __restrict__ rowptr, float2* __restrict__ entries) {
    int e = blockIdx.x * blockDim.x + threadIdx.x;
    if (e < N_EDGES) {
        int s = src[e], d = dst[e];
        float n = dinv[s] * w[e] * dinv[d];
        int pos = rowptr[d] + (int)rank[e];
        entries[pos] = make_float2(__int_as_float(s), n);
    }
}

// ---------------- per-layer kernels ----------------

// lin = h @ W   (layer 0 only; 256 thr = 4 rows x 64 cols; W staged in LDS)
__global__ void k_linear(const float* __restrict__ h, const float* __restrict__ W,
                         float* __restrict__ lin) {
    __shared__ float sW[HID * HID];
    __shared__ float sh[4][HID];
    int tid = threadIdx.x;
    for (int k = tid; k < HID * HID; k += 256) sW[k] = W[k];
    int r = tid >> 6, c = tid & 63;
    int row = blockIdx.x * 4 + r;
    if (row < N_NODES) sh[r][c] = h[(size_t)row * HID + c];
    __syncthreads();
    if (row < N_NODES) {
        float acc = 0.f;
#pragma unroll
        for (int k = 0; k < HID; ++k) acc = fmaf(sh[r][k], sW[k * HID + c], acc);
        lin[(size_t)row * HID + c] = acc;
    }
}

// gather-aggregate: one wave per node, lane = feature.
// out = relu( selfnorm*lin[node] + sum_e norm_e * lin[src_e] + b )
__global__ void k_gather(const float* __restrict__ lin, const float2* __restrict__ entries,
                         const int* __restrict__ rowptr, const float* __restrict__ selfnorm,
                         const float* __restrict__ b, float* __restrict__ out) {
    int wslot = __builtin_amdgcn_readfirstlane((int)(threadIdx.x >> 6));
    int node = blockIdx.x * 4 + wslot;
    int lane = threadIdx.x & 63;
    if (node >= N_NODES) return;
    float bl = b[lane];
    float acc = lin[(size_t)node * HID + lane] * selfnorm[node];
    int start = rowptr[node];
    int c = rowptr[node + 1] - start;
    const float2* ep = entries + start;
    int k = 0;
    for (; k + 7 < c; k += 8) {
        float2 e0 = ep[k],     e1 = ep[k + 1], e2 = ep[k + 2], e3 = ep[k + 3];
        float2 e4 = ep[k + 4], e5 = ep[k + 5], e6 = ep[k + 6], e7 = ep[k + 7];
        float v0 = lin[(size_t)__float_as_int(e0.x) * HID + lane];
        float v1 = lin[(size_t)__float_as_int(e1.x) * HID + lane];
        float v2 = lin[(size_t)__float_as_int(e2.x) * HID + lane];
        float v3 = lin[(size_t)__float_as_int(e3.x) * HID + lane];
        float v4 = lin[(size_t)__float_as_int(e4.x) * HID + lane];
        float v5 = lin[(size_t)__float_as_int(e5.x) * HID + lane];
        float v6 = lin[(size_t)__float_as_int(e6.x) * HID + lane];
        float v7 = lin[(size_t)__float_as_int(e7.x) * HID + lane];
        acc = fmaf(v0, e0.y, acc); acc = fmaf(v1, e1.y, acc);
        acc = fmaf(v2, e2.y, acc); acc = fmaf(v3, e3.y, acc);
        acc = fmaf(v4, e4.y, acc); acc = fmaf(v5, e5.y, acc);
        acc = fmaf(v6, e6.y, acc); acc = fmaf(v7, e7.y, acc);
    }
    for (; k + 1 < c; k += 2) {
        float2 e0 = ep[k], e1 = ep[k + 1];
        float v0 = lin[(size_t)__float_as_int(e0.x) * HID + lane];
        float v1 = lin[(size_t)__float_as_int(e1.x) * HID + lane];
        acc = fmaf(v0, e0.y, acc); acc = fmaf(v1, e1.y, acc);
    }
    if (k < c) {
        float2 e0 = ep[k];
        float v0 = lin[(size_t)__float_as_int(e0.x) * HID + lane];
        acc = fmaf(v0, e0.y, acc);
    }
    float t = acc + bl;
    out[(size_t)node * HID + lane] = t > 0.f ? t : 0.f;
}

// per-column sum/sumsq of h (already relu'd)
__global__ void k_bn_stats(const float* __restrict__ h, float* __restrict__ stats) {
    int c = threadIdx.x & 63, rr = threadIdx.x >> 6;
    float s = 0.f, s2 = 0.f;
    for (int row = blockIdx.x * 4 + rr; row < N_NODES; row += gridDim.x * 4) {
        float t = h[(size_t)row * HID + c];
        s += t; s2 += t * t;
    }
    __shared__ float ls[4][HID], ls2[4][HID];
    ls[rr][c] = s; ls2[rr][c] = s2;
    __syncthreads();
    if (threadIdx.x < HID) {
        atomicAdd(&stats[c],       ls[0][c] + ls[1][c] + ls[2][c] + ls[3][c]);
        atomicAdd(&stats[HID + c], ls2[0][c] + ls2[1][c] + ls2[2][c] + ls2[3][c]);
    }
}

// fused: h_norm = BN(h) written in place, AND lin_next = h_norm @ W_next
__global__ void k_bnlin(float* __restrict__ h, const float* __restrict__ gamma,
                        const float* __restrict__ beta, const float* __restrict__ stats,
                        const float* __restrict__ W, float* __restrict__ lin) {
    __shared__ float sW[HID * HID];
    __shared__ float sh[4][HID];
    int tid = threadIdx.x;
    for (int k = tid; k < HID * HID; k += 256) sW[k] = W[k];
    int r = tid >> 6, c = tid & 63;
    const float invn = 1.0f / (float)N_NODES;
    float mu = stats[c] * invn;
    float var = stats[HID + c] * invn - mu * mu;
    float sc = rsqrtf(var + BN_EPS) * gamma[c];
    float sf = beta[c] - mu * sc;
    int row = blockIdx.x * 4 + r;
    float val = 0.f;
    if (row < N_NODES) {
        val = h[(size_t)row * HID + c] * sc + sf;
        h[(size_t)row * HID + c] = val;      // final normalized output
    }
    sh[r][c] = val;
    __syncthreads();
    if (row < N_NODES) {
        float acc = 0.f;
#pragma unroll
        for (int k = 0; k < HID; ++k) acc = fmaf(sh[r][k], sW[k * HID + c], acc);
        lin[(size_t)row * HID + c] = acc;
    }
}

// last layer: BN in place only
__global__ void k_bn_apply(float* __restrict__ h, const float* __restrict__ gamma,
                           const float* __restrict__ beta, const float* __restrict__ stats) {
    int idx = blockIdx.x * blockDim.x + threadIdx.x;
    if (idx < N_NODES * HID) {
        int c = idx & 63;
        const float invn = 1.0f / (float)N_NODES;
        float mu = stats[c] * invn;
        float var = stats[HID + c] * invn - mu * mu;
        float ivar = rsqrtf(var + BN_EPS);
        h[idx] = (h[idx] - mu) * ivar * gamma[c] + beta[c];
    }
}

// ---------------- launch ----------------

extern "C" void kernel_launch(void* const* d_in, const int* in_sizes, int n_in,
                              void* d_out, int out_size, void* d_ws, size_t ws_size,
                              hipStream_t stream) {
    const float* x      = (const float*)d_in[0];   // [N, 64]
    const int*   ei     = (const int*)d_in[1];     // [2, E] int32
    const float* w      = (const float*)d_in[2];   // [E]
    const float* Ws     = (const float*)d_in[3];   // [3, 64, 64]
    const float* bs     = (const float*)d_in[4];   // [3, 64]
    const float* gammas = (const float*)d_in[5];   // [3, 64]
    const float* betas  = (const float*)d_in[6];   // [3, 64]
    float* out = (float*)d_out;                    // [3, N, 64] fp32

    const int* src = ei;
    const int* dst = ei + N_EDGES;

    // workspace layout (8B-aligned items first)
    float*  ws       = (float*)d_ws;
    float2* entries  = (float2*)ws;                                         // E * 8B
    unsigned long long* packed = (unsigned long long*)(ws + (size_t)2 * N_EDGES); // N * 8B
    float*  lin      = (float*)(packed + N_NODES);                          // N*64
    float*  dinv     = lin + (size_t)N_NODES * HID;                         // N
    float*  selfnorm = dinv + N_NODES;                                      // N
    int*    rowptr   = (int*)(selfnorm + N_NODES);                          // N+1
    int*    partials = rowptr + N_NODES + 1;                                // 256
    float*  stats    = (float*)(partials + 256);                            // 3 * 128
    unsigned char* rank = (unsigned char*)(stats + N_LAYERS * 2 * HID);     // E bytes

    const int T = 256;
    const int gN = (N_NODES + T - 1) / T;                     // 196
    const int gE = (N_EDGES + T - 1) / T;                     // 3125
    const int gR = (N_NODES + 3) / 4;                         // 12500
    const int gA = (N_NODES * HID + T - 1) / T;               // 12500

    // ---- graph-invariant precompute ----
    k_init<<<gN, T, 0, stream>>>(packed, stats);
    k_hist<<<gE, T, 0, stream>>>(dst, w, packed, rank);
    k_scan1<<<NB_SCAN, T, 0, stream>>>(packed, dinv, selfnorm, rowptr, partials);
    k_scan2<<<1, T, 0, stream>>>(partials);
    k_scan3<<<NB_SCAN, T, 0, stream>>>(rowptr, partials);
    k_fill<<<gE, T, 0, stream>>>(src, dst, w, dinv, rank, rowptr, entries);

    // ---- layers ----
    k_linear<<<gR, T, 0, stream>>>(x, Ws, lin);   // lin_0 = x @ W0
    for (int L = 0; L < N_LAYERS; ++L) {
        float* outL = out + (size_t)L * N_NODES * HID;
        const float* b  = bs + (size_t)L * HID;
        const float* g  = gammas + (size_t)L * HID;
        const float* bt = betas + (size_t)L * HID;
        float* statsL = stats + (size_t)L * 2 * HID;

        k_gather<<<gR, T, 0, stream>>>(lin, entries, rowptr, selfnorm, b, outL);
        k_bn_stats<<<256, T, 0, stream>>>(outL, statsL);
        if (L < N_LAYERS - 1) {
            const float* Wn = Ws + (size_t)(L + 1) * HID * HID;
            k_bnlin<<<gR, T, 0, stream>>>(outL, g, bt, statsL, Wn, lin);
        } else {
            k_bn_apply<<<gA, T, 0, stream>>>(outL, g, bt, statsL);
        }
    }
}